// Round 3
// baseline (416.881 us; speedup 1.0000x reference)
//
#include <hip/hip_runtime.h>
#include <hip/hip_bf16.h>
#include <stdint.h>

#define N_NODES_C 1000000
#define N_GRAPHS_C 4096

typedef __attribute__((ext_vector_type(8))) __bf16 bf16x8;
typedef __attribute__((ext_vector_type(2))) __bf16 bf16x2;
typedef __attribute__((ext_vector_type(4))) float f32x4;

__device__ __forceinline__ unsigned short f2bf(float f) {
    union { float f; unsigned int u; } v; v.f = f;
    unsigned int r = v.u + 0x7FFFu + ((v.u >> 16) & 1u);   // RNE
    return (unsigned short)(r >> 16);
}
__device__ __forceinline__ unsigned int pack2(float a, float b) {
#if __has_builtin(__builtin_amdgcn_cvt_pk_bf16_f32)
    bf16x2 r = __builtin_amdgcn_cvt_pk_bf16_f32(a, b);
    union { bf16x2 v; unsigned int u; } cv; cv.v = r;
    return cv.u;
#else
    return (unsigned int)f2bf(a) | ((unsigned int)f2bf(b) << 16);
#endif
}

// Stage 0: per-graph bias c[b][j] = bn[j] + (global_attr[b]@Wg + bg) @ Wn_bot[:,j]
// 4 graphs per 256-thread block; Wn_bot staged once per block in LDS.
// Block 0 additionally emits BT (Wn_top^T in bf16); every block zeroes its 4 denoms.
__global__ __launch_bounds__(256) void stage0_kernel(
    const float* __restrict__ ga, const float* __restrict__ Wg,
    const float* __restrict__ bg, const float* __restrict__ Wn,
    const float* __restrict__ bn,
    float* __restrict__ c, unsigned short* __restrict__ BT,
    float* __restrict__ denom)
{
    __shared__ float Wns[64 * 64];   // Wn rows 64..127 (16 KB)
    __shared__ float gs[4][64];
    int t = threadIdx.x;
#pragma unroll
    for (int i = 0; i < 4; ++i)
        ((float4*)Wns)[t + i * 256] = ((const float4*)(Wn + 64 * 64))[t + i * 256];
    if (blockIdx.x == 0) {
#pragma unroll
        for (int i = 0; i < 16; ++i) {
            int flat = t * 16 + i;           // BT[n][k] = Wn[k][n]
            int n = flat >> 6, k = flat & 63;
            BT[flat] = f2bf(Wn[k * 64 + n]);
        }
    }
    int gl = t >> 6, j = t & 63;
    int b = blockIdx.x * 4 + gl;
    float acc = bg[j];
#pragma unroll
    for (int m = 0; m < 3; ++m) acc += ga[b * 3 + m] * Wg[m * 64 + j];
    gs[gl][j] = acc;
    __syncthreads();
    float cj = bn[j];
#pragma unroll 16
    for (int k = 0; k < 64; ++k) cj += gs[gl][k] * Wns[k * 64 + j];
    c[b * 64 + j] = cj;
    if (j == 0) denom[b] = 0.0f;
}

// Main: one 16-node tile per wave. 62,500 tiles = 15,625 blocks x 4 waves EXACTLY
// (no bounds checks anywhere). All-register pipeline: x -> regs -> bf16 -> MFMA,
// fused softplus + Wa-dot + exp epilogue, e write + denom atomics. No LDS/barriers.
__global__ __launch_bounds__(256, 4) void node_kernel(
    const float* __restrict__ x, const int* __restrict__ nb,
    const float* __restrict__ c, const unsigned short* __restrict__ BT,
    const float* __restrict__ Wa, const float* __restrict__ ba,
    float* __restrict__ e, float* __restrict__ denom)
{
    int t = threadIdx.x;
    int wave = t >> 6, lane = t & 63;
    int quad = lane >> 4, l15 = lane & 15;
    int tile = blockIdx.x * 4 + wave;
    int base = tile * 16;                       // first node of this tile
    bool is64 = nb[N_NODES_C - 1] < 1024;       // int64 low/high-word layout vs int32

    // x loads: lane covers row base+l15, bytes quad*32..+16 and +16B, +128B phases
    const float4* xp = (const float4*)(x + (long)(base + l15) * 64);
    float4 v0 = xp[quad * 2];
    float4 v1 = xp[quad * 2 + 1];
    float4 v2 = xp[8 + quad * 2];
    float4 v3 = xp[8 + quad * 2 + 1];

    // Segment ids for this quad's 4 output rows (issue early; L2-hot)
    int r0 = base + quad * 4;
    int sg0, sg1, sg2, sg3;
    if (is64) {
        sg0 = nb[2L * (r0 + 0)]; sg1 = nb[2L * (r0 + 1)];
        sg2 = nb[2L * (r0 + 2)]; sg3 = nb[2L * (r0 + 3)];
    } else {
        sg0 = nb[r0 + 0]; sg1 = nb[r0 + 1];
        sg2 = nb[r0 + 2]; sg3 = nb[r0 + 3];
    }

    // B fragments: B[k][n], lane holds n = l15 (+16*nt), k = quad*8 + j (+32*kh)
    bf16x8 b0[4], b1[4];
#pragma unroll
    for (int nt = 0; nt < 4; ++nt) {
        b0[nt] = *(const bf16x8*)&BT[(nt * 16 + l15) * 64 + quad * 8];
        b1[nt] = *(const bf16x8*)&BT[(nt * 16 + l15) * 64 + quad * 8 + 32];
    }
    float wa[4];
    float bav = ba[0];
#pragma unroll
    for (int nt = 0; nt < 4; ++nt) wa[nt] = Wa[nt * 16 + l15];

    union { bf16x8 v; unsigned int u[4]; } A0, A1;
    A0.u[0] = pack2(v0.x, v0.y); A0.u[1] = pack2(v0.z, v0.w);
    A0.u[2] = pack2(v1.x, v1.y); A0.u[3] = pack2(v1.z, v1.w);
    A1.u[0] = pack2(v2.x, v2.y); A1.u[1] = pack2(v2.z, v2.w);
    A1.u[2] = pack2(v3.x, v3.y); A1.u[3] = pack2(v3.z, v3.w);

    f32x4 acc[4];
#pragma unroll
    for (int nt = 0; nt < 4; ++nt) {
        acc[nt] = (f32x4){0.f, 0.f, 0.f, 0.f};
        acc[nt] = __builtin_amdgcn_mfma_f32_16x16x32_bf16(A0.v, b0[nt], acc[nt], 0, 0, 0);
        acc[nt] = __builtin_amdgcn_mfma_f32_16x16x32_bf16(A1.v, b1[nt], acc[nt], 0, 0, 0);
    }

    // Epilogue. C/D layout: col = l15 + 16*nt, rows = base + quad*4 + reg
    bool uni = (sg0 == sg3);                    // sorted -> ends equal => all equal
    float sp0 = 0.f, sp1 = 0.f, sp2 = 0.f, sp3 = 0.f;
#pragma unroll
    for (int nt = 0; nt < 4; ++nt) {
        int col = nt * 16 + l15;
        float c0, c1, c2, c3;
        if (uni) { c0 = c[sg0 * 64 + col]; c1 = c0; c2 = c0; c3 = c0; }
        else {
            c0 = c[sg0 * 64 + col]; c1 = c[sg1 * 64 + col];
            c2 = c[sg2 * 64 + col]; c3 = c[sg3 * 64 + col];
        }
        float y0 = acc[nt].x + c0, y1 = acc[nt].y + c1;
        float y2 = acc[nt].z + c2, y3 = acc[nt].w + c3;
        sp0 += __logf(1.f + __expf(y0)) * wa[nt];
        sp1 += __logf(1.f + __expf(y1)) * wa[nt];
        sp2 += __logf(1.f + __expf(y2)) * wa[nt];
        sp3 += __logf(1.f + __expf(y3)) * wa[nt];
    }
#pragma unroll
    for (int off = 1; off < 16; off <<= 1) {    // xor 1,2,4,8 stays inside the quad
        sp0 += __shfl_xor(sp0, off, 64);
        sp1 += __shfl_xor(sp1, off, 64);
        sp2 += __shfl_xor(sp2, off, 64);
        sp3 += __shfl_xor(sp3, off, 64);
    }
    float e0 = __expf(sp0 + bav), e1 = __expf(sp1 + bav);
    float e2 = __expf(sp2 + bav), e3 = __expf(sp3 + bav);
    if (l15 == 0) {
        *(float4*)&e[r0] = make_float4(e0, e1, e2, e3);
        float s = e0; int cur = sg0;
        if (sg1 == cur) s += e1; else { atomicAdd(&denom[cur], s); cur = sg1; s = e1; }
        if (sg2 == cur) s += e2; else { atomicAdd(&denom[cur], s); cur = sg2; s = e2; }
        if (sg3 == cur) s += e3; else { atomicAdd(&denom[cur], s); cur = sg3; s = e3; }
        atomicAdd(&denom[cur], s);
    }
}

// Finalize: w = e / denom[seg]
__global__ __launch_bounds__(256) void fin_kernel(
    const float* __restrict__ e, const int* __restrict__ nb,
    const float* __restrict__ denom, float* __restrict__ out)
{
    long node0 = (long)(blockIdx.x * 256 + threadIdx.x) * 4;
    if (node0 >= N_NODES_C) return;
    bool is64 = nb[N_NODES_C - 1] < 1024;
    float4 ev = *(const float4*)&e[node0];
    int s0, s1, s2, s3;
    if (is64) {
        int4 a = *(const int4*)&nb[2 * node0];
        int4 b = *(const int4*)&nb[2 * node0 + 4];
        s0 = a.x; s1 = a.z; s2 = b.x; s3 = b.z;
    } else {
        int4 a = *(const int4*)&nb[node0];
        s0 = a.x; s1 = a.y; s2 = a.z; s3 = a.w;
    }
    float4 w;
    w.x = ev.x / denom[s0];
    w.y = ev.y / denom[s1];
    w.z = ev.z / denom[s2];
    w.w = ev.w / denom[s3];
    *(float4*)&out[node0] = w;
}

extern "C" void kernel_launch(void* const* d_in, const int* in_sizes, int n_in,
                              void* d_out, int out_size, void* d_ws, size_t ws_size,
                              hipStream_t stream) {
    const float* x  = (const float*)d_in[0];
    const int*   nb = (const int*)d_in[1];
    const float* ga = (const float*)d_in[2];
    const float* Wg = (const float*)d_in[3];
    const float* bg = (const float*)d_in[4];
    const float* Wn = (const float*)d_in[5];
    const float* bn = (const float*)d_in[6];
    const float* Wa = (const float*)d_in[7];
    const float* ba = (const float*)d_in[8];

    char* ws = (char*)d_ws;
    float* e            = (float*)(ws);                              // 4,000,000 B
    float* c            = (float*)(ws + 4194304);                    // 1 MB
    unsigned short* BT  = (unsigned short*)(ws + 4194304 + 1048576); // 8 KB
    float* denom        = (float*)(ws + 4194304 + 1048576 + 8192);   // 16 KB

    hipLaunchKernelGGL(stage0_kernel, dim3(N_GRAPHS_C / 4), dim3(256), 0, stream,
                       ga, Wg, bg, Wn, bn, c, BT, denom);
    hipLaunchKernelGGL(node_kernel, dim3(N_NODES_C / 64), dim3(256), 0, stream,
                       x, nb, c, BT, Wa, ba, e, denom);
    hipLaunchKernelGGL(fin_kernel, dim3((N_NODES_C / 4 + 255) / 256), dim3(256), 0, stream,
                       e, nb, denom, (float*)d_out);
}

// Round 4
// 375.838 us; speedup vs baseline: 1.1092x; 1.1092x over previous
//
#include <hip/hip_runtime.h>
#include <hip/hip_bf16.h>
#include <stdint.h>

#define N_NODES_C 1000000
#define N_GRAPHS_C 4096
#define SPAN 96   // block-local denom table: 64 consecutive nodes span <=2 graphs (96 = margin)

typedef __attribute__((ext_vector_type(8))) __bf16 bf16x8;
typedef __attribute__((ext_vector_type(2))) __bf16 bf16x2;
typedef __attribute__((ext_vector_type(4))) float f32x4;

__device__ __forceinline__ unsigned short f2bf(float f) {
    union { float f; unsigned int u; } v; v.f = f;
    unsigned int r = v.u + 0x7FFFu + ((v.u >> 16) & 1u);   // RNE
    return (unsigned short)(r >> 16);
}
__device__ __forceinline__ unsigned int pack2(float a, float b) {
#if __has_builtin(__builtin_amdgcn_cvt_pk_bf16_f32)
    bf16x2 r = __builtin_amdgcn_cvt_pk_bf16_f32(a, b);
    union { bf16x2 v; unsigned int u; } cv; cv.v = r;
    return cv.u;
#else
    return (unsigned int)f2bf(a) | ((unsigned int)f2bf(b) << 16);
#endif
}

// Stage 0: per-graph bias c[b][j] = bn[j] + (global_attr[b]@Wg + bg) @ Wn_bot[:,j]
// 4 graphs per 256-thread block; Wn_bot staged once per block in LDS.
// Block 0 additionally emits BT (Wn_top^T in bf16); every block zeroes its 4 denoms.
__global__ __launch_bounds__(256) void stage0_kernel(
    const float* __restrict__ ga, const float* __restrict__ Wg,
    const float* __restrict__ bg, const float* __restrict__ Wn,
    const float* __restrict__ bn,
    float* __restrict__ c, unsigned short* __restrict__ BT,
    float* __restrict__ denom)
{
    __shared__ float Wns[64 * 64];   // Wn rows 64..127 (16 KB)
    __shared__ float gs[4][64];
    int t = threadIdx.x;
#pragma unroll
    for (int i = 0; i < 4; ++i)
        ((float4*)Wns)[t + i * 256] = ((const float4*)(Wn + 64 * 64))[t + i * 256];
    if (blockIdx.x == 0) {
#pragma unroll
        for (int i = 0; i < 16; ++i) {
            int flat = t * 16 + i;           // BT[n][k] = Wn[k][n]
            int n = flat >> 6, k = flat & 63;
            BT[flat] = f2bf(Wn[k * 64 + n]);
        }
    }
    int gl = t >> 6, j = t & 63;
    int b = blockIdx.x * 4 + gl;
    float acc = bg[j];
#pragma unroll
    for (int m = 0; m < 3; ++m) acc += ga[b * 3 + m] * Wg[m * 64 + j];
    gs[gl][j] = acc;
    __syncthreads();
    float cj = bn[j];
#pragma unroll 16
    for (int k = 0; k < 64; ++k) cj += gs[gl][k] * Wns[k * 64 + j];
    c[b * 64 + j] = cj;
    if (j == 0) denom[b] = 0.0f;
}

// Main: one 16-node tile per wave, 4 waves/block = 64 nodes/block, exact grid.
// All-register MFMA pipeline; denom contributions aggregated per-block in LDS
// (sorted segments -> block spans ~1-2 graphs), then ~1-2 global atomics/block.
__global__ __launch_bounds__(256, 8) void node_kernel(
    const float* __restrict__ x, const int* __restrict__ nb,
    const float* __restrict__ c, const unsigned short* __restrict__ BT,
    const float* __restrict__ Wa, const float* __restrict__ ba,
    float* __restrict__ e, float* __restrict__ denom)
{
    __shared__ float part[SPAN];
    int t = threadIdx.x;
    int wave = t >> 6, lane = t & 63;
    int quad = lane >> 4, l15 = lane & 15;
    int blockbase = blockIdx.x * 64;
    int base = blockbase + wave * 16;           // first node of this tile
    bool is64 = nb[N_NODES_C - 1] < 1024;       // int64 low/high-word layout vs int32

    if (t < SPAN) part[t] = 0.0f;

    // x loads: lane covers row base+l15, 4x float4
    const float4* xp = (const float4*)(x + (long)(base + l15) * 64);
    float4 v0 = xp[quad * 2];
    float4 v1 = xp[quad * 2 + 1];
    float4 v2 = xp[8 + quad * 2];
    float4 v3 = xp[8 + quad * 2 + 1];

    // Segment ids: one coalesced load (lane l15 -> row base+l15), distribute by shuffle
    int g0 = is64 ? nb[2L * blockbase] : nb[blockbase];
    int segown = is64 ? nb[2L * (base + l15)] : nb[base + l15];
    int sg0 = __shfl(segown, quad * 4 + 0, 64);
    int sg1 = __shfl(segown, quad * 4 + 1, 64);
    int sg2 = __shfl(segown, quad * 4 + 2, 64);
    int sg3 = __shfl(segown, quad * 4 + 3, 64);

    // B fragments: B[k][n], lane holds n = l15 (+16*nt), k = quad*8 + j (+32*kh)
    bf16x8 b0[4], b1[4];
#pragma unroll
    for (int nt = 0; nt < 4; ++nt) {
        b0[nt] = *(const bf16x8*)&BT[(nt * 16 + l15) * 64 + quad * 8];
        b1[nt] = *(const bf16x8*)&BT[(nt * 16 + l15) * 64 + quad * 8 + 32];
    }
    float wa[4];
    float bav = ba[0];
#pragma unroll
    for (int nt = 0; nt < 4; ++nt) wa[nt] = Wa[nt * 16 + l15];

    union { bf16x8 v; unsigned int u[4]; } A0, A1;
    A0.u[0] = pack2(v0.x, v0.y); A0.u[1] = pack2(v0.z, v0.w);
    A0.u[2] = pack2(v1.x, v1.y); A0.u[3] = pack2(v1.z, v1.w);
    A1.u[0] = pack2(v2.x, v2.y); A1.u[1] = pack2(v2.z, v2.w);
    A1.u[2] = pack2(v3.x, v3.y); A1.u[3] = pack2(v3.z, v3.w);

    __syncthreads();   // part[] zeroed before any leader writes

    f32x4 acc[4];
#pragma unroll
    for (int nt = 0; nt < 4; ++nt) {
        acc[nt] = (f32x4){0.f, 0.f, 0.f, 0.f};
        acc[nt] = __builtin_amdgcn_mfma_f32_16x16x32_bf16(A0.v, b0[nt], acc[nt], 0, 0, 0);
        acc[nt] = __builtin_amdgcn_mfma_f32_16x16x32_bf16(A1.v, b1[nt], acc[nt], 0, 0, 0);
    }

    // Epilogue. C/D layout: col = l15 + 16*nt, rows = base + quad*4 + reg
    int r0 = base + quad * 4;
    bool uni = (sg0 == sg3);                    // sorted -> ends equal => all equal
    float sp0 = 0.f, sp1 = 0.f, sp2 = 0.f, sp3 = 0.f;
#pragma unroll
    for (int nt = 0; nt < 4; ++nt) {
        int col = nt * 16 + l15;
        float c0, c1, c2, c3;
        if (uni) { c0 = c[sg0 * 64 + col]; c1 = c0; c2 = c0; c3 = c0; }
        else {
            c0 = c[sg0 * 64 + col]; c1 = c[sg1 * 64 + col];
            c2 = c[sg2 * 64 + col]; c3 = c[sg3 * 64 + col];
        }
        float y0 = acc[nt].x + c0, y1 = acc[nt].y + c1;
        float y2 = acc[nt].z + c2, y3 = acc[nt].w + c3;
        sp0 += __logf(1.f + __expf(y0)) * wa[nt];
        sp1 += __logf(1.f + __expf(y1)) * wa[nt];
        sp2 += __logf(1.f + __expf(y2)) * wa[nt];
        sp3 += __logf(1.f + __expf(y3)) * wa[nt];
    }
#pragma unroll
    for (int off = 1; off < 16; off <<= 1) {    // xor 1,2,4,8 stays inside the quad
        sp0 += __shfl_xor(sp0, off, 64);
        sp1 += __shfl_xor(sp1, off, 64);
        sp2 += __shfl_xor(sp2, off, 64);
        sp3 += __shfl_xor(sp3, off, 64);
    }
    float e0 = __expf(sp0 + bav), e1 = __expf(sp1 + bav);
    float e2 = __expf(sp2 + bav), e3 = __expf(sp3 + bav);
    if (l15 == 0) {
        *(float4*)&e[r0] = make_float4(e0, e1, e2, e3);
        // merge runs, then LDS-aggregate (global fallback only if span exceeded: ~never)
        float s = e0; int cur = sg0;
        if (sg1 == cur) s += e1; else {
            unsigned int i0 = cur - g0;
            if (i0 < SPAN) atomicAdd(&part[i0], s); else atomicAdd(&denom[cur], s);
            cur = sg1; s = e1;
        }
        if (sg2 == cur) s += e2; else {
            unsigned int i0 = cur - g0;
            if (i0 < SPAN) atomicAdd(&part[i0], s); else atomicAdd(&denom[cur], s);
            cur = sg2; s = e2;
        }
        if (sg3 == cur) s += e3; else {
            unsigned int i0 = cur - g0;
            if (i0 < SPAN) atomicAdd(&part[i0], s); else atomicAdd(&denom[cur], s);
            cur = sg3; s = e3;
        }
        unsigned int i0 = cur - g0;
        if (i0 < SPAN) atomicAdd(&part[i0], s); else atomicAdd(&denom[cur], s);
    }
    __syncthreads();
    if (t < SPAN) {
        float v = part[t];
        if (v != 0.0f) atomicAdd(&denom[g0 + t], v);
    }
}

// Finalize: w = e / denom[seg]
__global__ __launch_bounds__(256) void fin_kernel(
    const float* __restrict__ e, const int* __restrict__ nb,
    const float* __restrict__ denom, float* __restrict__ out)
{
    long node0 = (long)(blockIdx.x * 256 + threadIdx.x) * 4;
    if (node0 >= N_NODES_C) return;
    bool is64 = nb[N_NODES_C - 1] < 1024;
    float4 ev = *(const float4*)&e[node0];
    int s0, s1, s2, s3;
    if (is64) {
        int4 a = *(const int4*)&nb[2 * node0];
        int4 b = *(const int4*)&nb[2 * node0 + 4];
        s0 = a.x; s1 = a.z; s2 = b.x; s3 = b.z;
    } else {
        int4 a = *(const int4*)&nb[node0];
        s0 = a.x; s1 = a.y; s2 = a.z; s3 = a.w;
    }
    float4 w;
    w.x = ev.x / denom[s0];
    w.y = ev.y / denom[s1];
    w.z = ev.z / denom[s2];
    w.w = ev.w / denom[s3];
    *(float4*)&out[node0] = w;
}

extern "C" void kernel_launch(void* const* d_in, const int* in_sizes, int n_in,
                              void* d_out, int out_size, void* d_ws, size_t ws_size,
                              hipStream_t stream) {
    const float* x  = (const float*)d_in[0];
    const int*   nb = (const int*)d_in[1];
    const float* ga = (const float*)d_in[2];
    const float* Wg = (const float*)d_in[3];
    const float* bg = (const float*)d_in[4];
    const float* Wn = (const float*)d_in[5];
    const float* bn = (const float*)d_in[6];
    const float* Wa = (const float*)d_in[7];
    const float* ba = (const float*)d_in[8];

    char* ws = (char*)d_ws;
    float* e            = (float*)(ws);                              // 4,000,000 B
    float* c            = (float*)(ws + 4194304);                    // 1 MB
    unsigned short* BT  = (unsigned short*)(ws + 4194304 + 1048576); // 8 KB
    float* denom        = (float*)(ws + 4194304 + 1048576 + 8192);   // 16 KB

    hipLaunchKernelGGL(stage0_kernel, dim3(N_GRAPHS_C / 4), dim3(256), 0, stream,
                       ga, Wg, bg, Wn, bn, c, BT, denom);
    hipLaunchKernelGGL(node_kernel, dim3(N_NODES_C / 64), dim3(256), 0, stream,
                       x, nb, c, BT, Wa, ba, e, denom);
    hipLaunchKernelGGL(fin_kernel, dim3((N_NODES_C / 4 + 255) / 256), dim3(256), 0, stream,
                       e, nb, denom, (float*)d_out);
}